// Round 2
// baseline (798.886 us; speedup 1.0000x reference)
//
#include <hip/hip_runtime.h>
#include <hip/hip_bf16.h>

// Problem: B=4,S=2048 -> T=8192 tokens, EMB=1024, HID=2048, E=8, top-2 MoE.
// out = [top2_weights (T*2 f32)] ++ [top2_expert_outputs (T*2*HID f32)]
// Only top-2 expert outputs are needed -> grouped GEMM over expert-assigned
// token lists (4x FLOP reduction vs dense reference).

#define T_TOKENS 8192
#define EMBD 1024
#define HIDD 2048
#define NEXP 8

#define BM 64
#define BN 64
#define BKT 64
#define LDT 72            // padded LDS row stride (bf16 elems) to spread banks
#define MAX_TILES 264     // sum ceil(cnt_e/BM) <= 16384/64 + 8

// ws int layout
#define WS_COUNTS 0       // [8]
#define WS_NTILES 8       // [1]
#define WS_TDESC 16       // [264*2] (expert, m0)
#define WS_SLOTS 1024     // [8][16384] slot = token*2 + k

typedef __attribute__((ext_vector_type(8))) short short8;
typedef __attribute__((ext_vector_type(4))) float f32x4;

__device__ inline unsigned pack2_bf16(float a, float b) {
  unsigned ua = __float_as_uint(a);
  unsigned ub = __float_as_uint(b);
  ua = (ua + 0x7FFFu + ((ua >> 16) & 1u)) >> 16;   // RNE
  ub = (ub + 0x7FFFu + ((ub >> 16) & 1u)) >> 16;
  return ua | (ub << 16);
}

__device__ inline unsigned short bf16_1(float a) {
  unsigned ua = __float_as_uint(a);
  return (unsigned short)((ua + 0x7FFFu + ((ua >> 16) & 1u)) >> 16);
}

// ---------------- gating: logits -> softmax -> top2 + expert lists ----------
__global__ __launch_bounds__(256) void gate_kernel(
    const float* __restrict__ x, const float* __restrict__ Wg,
    const float* __restrict__ bg, float* __restrict__ out,
    int* __restrict__ ws) {
  int wid = threadIdx.x >> 6;
  int lane = threadIdx.x & 63;
  int t = blockIdx.x * 4 + wid;
  if (t >= T_TOKENS) return;
  const float* xr = x + (size_t)t * EMBD;
  float acc[8];
#pragma unroll
  for (int e = 0; e < 8; ++e) acc[e] = 0.f;
  for (int i = lane; i < EMBD; i += 64) {
    float xv = xr[i];
    float4 w0 = *(const float4*)(Wg + (size_t)i * 8);
    float4 w1 = *(const float4*)(Wg + (size_t)i * 8 + 4);
    acc[0] += xv * w0.x; acc[1] += xv * w0.y;
    acc[2] += xv * w0.z; acc[3] += xv * w0.w;
    acc[4] += xv * w1.x; acc[5] += xv * w1.y;
    acc[6] += xv * w1.z; acc[7] += xv * w1.w;
  }
#pragma unroll
  for (int off = 32; off > 0; off >>= 1) {
#pragma unroll
    for (int e = 0; e < 8; ++e) acc[e] += __shfl_xor(acc[e], off);
  }
  if (lane == 0) {
    float lg[8];
#pragma unroll
    for (int e = 0; e < 8; ++e) lg[e] = acc[e] + bg[e];
    float mx = lg[0];
#pragma unroll
    for (int e = 1; e < 8; ++e) mx = fmaxf(mx, lg[e]);
    float w[8];
    float s = 0.f;
#pragma unroll
    for (int e = 0; e < 8; ++e) { w[e] = expf(lg[e] - mx); s += w[e]; }
    float inv = 1.f / s;
    // top-2 with lowest-index tie-break (matches lax.top_k)
    int i0 = 0;
#pragma unroll
    for (int e = 1; e < 8; ++e) if (lg[e] > lg[i0]) i0 = e;
    int i1 = (i0 == 0) ? 1 : 0;
#pragma unroll
    for (int e = 0; e < 8; ++e) if (e != i0 && lg[e] > lg[i1]) i1 = e;
    out[(size_t)t * 2] = w[i0] * inv;
    out[(size_t)t * 2 + 1] = w[i1] * inv;
    int p0 = atomicAdd(&ws[WS_COUNTS + i0], 1);
    ws[WS_SLOTS + i0 * 16384 + p0] = t * 2;
    int p1 = atomicAdd(&ws[WS_COUNTS + i1], 1);
    ws[WS_SLOTS + i1 * 16384 + p1] = t * 2 + 1;
  }
}

// ---------------- scheduler: counts -> tile descriptors --------------------
__global__ void sched_kernel(int* __restrict__ ws) {
  if (threadIdx.x == 0 && blockIdx.x == 0) {
    int nt = 0;
    for (int e = 0; e < NEXP; ++e) {
      int c = ws[WS_COUNTS + e];
      for (int m0 = 0; m0 < c; m0 += BM) {
        ws[WS_TDESC + nt * 2] = e;
        ws[WS_TDESC + nt * 2 + 1] = m0;
        ++nt;
      }
    }
    ws[WS_NTILES] = nt;
  }
}

// ---------------- grouped expert GEMM (bf16 MFMA) ---------------------------
__global__ __launch_bounds__(256) void expert_kernel(
    const float* __restrict__ x, const float* __restrict__ We,
    const float* __restrict__ be, const int* __restrict__ ws,
    float* __restrict__ out) {
  __shared__ short As[BM * LDT];
  __shared__ short Bs[BN * LDT];
  __shared__ int sslot[BM];

  int nt = ws[WS_NTILES];
  if ((int)blockIdx.x >= nt) return;
  int e = ws[WS_TDESC + blockIdx.x * 2];
  int m0 = ws[WS_TDESC + blockIdx.x * 2 + 1];
  int cnt = ws[WS_COUNTS + e];
  int n0 = blockIdx.y * BN;

  int tid = threadIdx.x;
  if (tid < BM) {
    int slot = -1;
    if (m0 + tid < cnt) slot = ws[WS_SLOTS + e * 16384 + m0 + tid];
    sslot[tid] = slot;
  }
  __syncthreads();

  int lane = tid & 63;
  int wid = tid >> 6;
  int wr = wid >> 1, wc = wid & 1;
  int lrow = lane & 15, lgrp = lane >> 4;

  f32x4 acc[2][2];
#pragma unroll
  for (int mi = 0; mi < 2; ++mi)
#pragma unroll
    for (int ni = 0; ni < 2; ++ni) acc[mi][ni] = (f32x4){0.f, 0.f, 0.f, 0.f};

  // A staging assignment: thread -> (row, 16-col chunk)
  int arow = tid >> 2;
  int acq = (tid & 3) * 16;
  int aslot = sslot[arow];
  const float* abase =
      (aslot >= 0) ? (x + (size_t)(aslot >> 1) * EMBD + acq) : x;

  // B staging assignment: thread -> (k row, 16-col chunk), transpose to [n][k]
  int bk = tid >> 2;
  int bnq = (tid & 3) * 16;
  const float* wbase =
      We + (size_t)e * EMBD * HIDD + (size_t)bk * HIDD + n0 + bnq;

#pragma unroll 1
  for (int ks = 0; ks < EMBD / BKT; ++ks) {
    int k0 = ks * BKT;
    // ---- stage A [BM][BKT] f32 -> bf16 LDS
    {
      unsigned pk[8];
      if (aslot >= 0) {
        const float4* p = (const float4*)(abase + k0);
        float4 f0 = p[0], f1 = p[1], f2 = p[2], f3 = p[3];
        pk[0] = pack2_bf16(f0.x, f0.y); pk[1] = pack2_bf16(f0.z, f0.w);
        pk[2] = pack2_bf16(f1.x, f1.y); pk[3] = pack2_bf16(f1.z, f1.w);
        pk[4] = pack2_bf16(f2.x, f2.y); pk[5] = pack2_bf16(f2.z, f2.w);
        pk[6] = pack2_bf16(f3.x, f3.y); pk[7] = pack2_bf16(f3.z, f3.w);
      } else {
#pragma unroll
        for (int i = 0; i < 8; ++i) pk[i] = 0u;
      }
      int4* dst = (int4*)&As[arow * LDT + acq];
      dst[0] = make_int4((int)pk[0], (int)pk[1], (int)pk[2], (int)pk[3]);
      dst[1] = make_int4((int)pk[4], (int)pk[5], (int)pk[6], (int)pk[7]);
    }
    // ---- stage B [BKT][BN] f32 -> transposed bf16 LDS [BN][BKT]
    {
      const float4* p = (const float4*)(wbase + (size_t)k0 * HIDD);
      float4 f0 = p[0], f1 = p[1], f2 = p[2], f3 = p[3];
      float v[16] = {f0.x, f0.y, f0.z, f0.w, f1.x, f1.y, f1.z, f1.w,
                     f2.x, f2.y, f2.z, f2.w, f3.x, f3.y, f3.z, f3.w};
#pragma unroll
      for (int j = 0; j < 16; ++j)
        Bs[(bnq + j) * LDT + bk] = (short)bf16_1(v[j]);
    }
    __syncthreads();
    // ---- MFMA
#pragma unroll
    for (int kk = 0; kk < 2; ++kk) {
      short8 a0 = *(const short8*)&As[(wr * 32 + 0 + lrow) * LDT + kk * 32 + lgrp * 8];
      short8 a1 = *(const short8*)&As[(wr * 32 + 16 + lrow) * LDT + kk * 32 + lgrp * 8];
      short8 b0 = *(const short8*)&Bs[(wc * 32 + 0 + lrow) * LDT + kk * 32 + lgrp * 8];
      short8 b1 = *(const short8*)&Bs[(wc * 32 + 16 + lrow) * LDT + kk * 32 + lgrp * 8];
      acc[0][0] = __builtin_amdgcn_mfma_f32_16x16x32_bf16(a0, b0, acc[0][0], 0, 0, 0);
      acc[0][1] = __builtin_amdgcn_mfma_f32_16x16x32_bf16(a0, b1, acc[0][1], 0, 0, 0);
      acc[1][0] = __builtin_amdgcn_mfma_f32_16x16x32_bf16(a1, b0, acc[1][0], 0, 0, 0);
      acc[1][1] = __builtin_amdgcn_mfma_f32_16x16x32_bf16(a1, b1, acc[1][1], 0, 0, 0);
    }
    __syncthreads();
  }

  // ---- epilogue: D layout col=lane&15, row=(lane>>4)*4+reg (verified m89/m91)
#pragma unroll
  for (int ni = 0; ni < 2; ++ni) {
    int colg = n0 + wc * 32 + ni * 16 + lrow;
    float bev = be[(size_t)e * HIDD + colg];
#pragma unroll
    for (int mi = 0; mi < 2; ++mi) {
#pragma unroll
      for (int r = 0; r < 4; ++r) {
        int m = wr * 32 + mi * 16 + lgrp * 4 + r;
        int slot = sslot[m];
        if (slot >= 0)
          out[(size_t)T_TOKENS * 2 + (size_t)slot * HIDD + colg] =
              acc[mi][ni][r] + bev;
      }
    }
  }
}

extern "C" void kernel_launch(void* const* d_in, const int* in_sizes, int n_in,
                              void* d_out, int out_size, void* d_ws,
                              size_t ws_size, hipStream_t stream) {
  const float* x = (const float*)d_in[0];
  const float* Wg = (const float*)d_in[1];
  const float* bg = (const float*)d_in[2];
  const float* We = (const float*)d_in[3];
  const float* be = (const float*)d_in[4];
  float* out = (float*)d_out;
  int* ws = (int*)d_ws;

  // zero counts + ntiles (ws is re-poisoned to 0xAA before every launch)
  hipMemsetAsync(d_ws, 0, 64, stream);
  gate_kernel<<<T_TOKENS / 4, 256, 0, stream>>>(x, Wg, bg, out, ws);
  sched_kernel<<<1, 64, 0, stream>>>(ws);
  expert_kernel<<<dim3(MAX_TILES, HIDD / BN, 1), 256, 0, stream>>>(x, We, be,
                                                                   ws, out);
}

// Round 3
// 422.199 us; speedup vs baseline: 1.8922x; 1.8922x over previous
//
#include <hip/hip_runtime.h>
#include <hip/hip_bf16.h>

// B=4,S=2048 -> T=8192 tokens, EMB=1024, HID=2048, E=8, top-2 MoE.
// out = [top2_weights (T*2 f32)] ++ [top2_expert_outputs (T*2*HID f32)]

#define T_TOKENS 8192
#define EMBD 1024
#define HIDD 2048
#define NEXP 8

// ws int layout (lists region, < 600 KB)
#define WS_COUNTS 0        // [8]
#define WS_NTILES 8        // [1]
#define WS_TDESC 16        // [264*2] (expert, m0)
#define WS_EIDS 1024       // [8192] packed i0|i1<<8
#define WS_SLOTS 17408     // [8][16384] slot = token*2 + k

// bf16 scratch region (fast path)
#define X_BF_OFF ((size_t)1 << 20)                    // 16,777,216 B
#define WE_BF_OFF (X_BF_OFF + (size_t)16777216)       // 33,554,432 B
#define WS_NEED (WE_BF_OFF + (size_t)33554432)        // ~51.4 MB

typedef __attribute__((ext_vector_type(8))) short short8;
typedef __attribute__((ext_vector_type(4))) float f32x4;

__device__ __forceinline__ unsigned pack2_bf16(float a, float b) {
  unsigned ua = __float_as_uint(a);
  unsigned ub = __float_as_uint(b);
  ua = (ua + 0x7FFFu + ((ua >> 16) & 1u)) >> 16;  // RNE
  ub = (ub + 0x7FFFu + ((ub >> 16) & 1u)) >> 16;
  return ua | (ub << 16);
}

__device__ __forceinline__ unsigned short bf16_1(float a) {
  unsigned ua = __float_as_uint(a);
  return (unsigned short)((ua + 0x7FFFu + ((ua >> 16) & 1u)) >> 16);
}

typedef __attribute__((address_space(3))) unsigned lds_u32;
typedef const __attribute__((address_space(1))) unsigned glb_u32;
__device__ __forceinline__ void g2lds16(const void* g, void* l) {
  __builtin_amdgcn_global_load_lds((glb_u32*)g, (lds_u32*)l, 16, 0, 0);
}

// ---------------- gating: logits -> softmax -> top2 (NO atomics) ------------
__global__ __launch_bounds__(256) void gate_kernel(
    const float* __restrict__ x, const float* __restrict__ Wg,
    const float* __restrict__ bg, float* __restrict__ out,
    int* __restrict__ ws) {
  int wid = threadIdx.x >> 6;
  int lane = threadIdx.x & 63;
  int t = blockIdx.x * 4 + wid;
  if (t >= T_TOKENS) return;
  const float* xr = x + (size_t)t * EMBD;
  float acc[8];
#pragma unroll
  for (int e = 0; e < 8; ++e) acc[e] = 0.f;
  for (int i = lane; i < EMBD; i += 64) {
    float xv = xr[i];
    float4 w0 = *(const float4*)(Wg + (size_t)i * 8);
    float4 w1 = *(const float4*)(Wg + (size_t)i * 8 + 4);
    acc[0] += xv * w0.x; acc[1] += xv * w0.y;
    acc[2] += xv * w0.z; acc[3] += xv * w0.w;
    acc[4] += xv * w1.x; acc[5] += xv * w1.y;
    acc[6] += xv * w1.z; acc[7] += xv * w1.w;
  }
#pragma unroll
  for (int off = 32; off > 0; off >>= 1) {
#pragma unroll
    for (int e = 0; e < 8; ++e) acc[e] += __shfl_xor(acc[e], off);
  }
  if (lane == 0) {
    float lg[8];
#pragma unroll
    for (int e = 0; e < 8; ++e) lg[e] = acc[e] + bg[e];
    float mx = lg[0];
#pragma unroll
    for (int e = 1; e < 8; ++e) mx = fmaxf(mx, lg[e]);
    float w[8];
    float s = 0.f;
#pragma unroll
    for (int e = 0; e < 8; ++e) { w[e] = expf(lg[e] - mx); s += w[e]; }
    float inv = 1.f / s;
    int i0 = 0;
#pragma unroll
    for (int e = 1; e < 8; ++e) if (lg[e] > lg[i0]) i0 = e;
    int i1 = (i0 == 0) ? 1 : 0;
#pragma unroll
    for (int e = 0; e < 8; ++e) if (e != i0 && lg[e] > lg[i1]) i1 = e;
    out[(size_t)t * 2] = w[i0] * inv;
    out[(size_t)t * 2 + 1] = w[i1] * inv;
    ws[WS_EIDS + t] = i0 | (i1 << 8);
  }
}

// ---------------- list build: per-expert stable compaction ------------------
__global__ __launch_bounds__(256) void lists_kernel(int* __restrict__ ws) {
  int e = blockIdx.x;
  int tid = threadIdx.x;
  int lane = tid & 63, wid = tid >> 6;
  __shared__ int wsum[4];
  __shared__ int cursor;
  if (tid == 0) cursor = 0;
  __syncthreads();
  int pk = ws[WS_EIDS + (tid >> 1)];
  for (int it = 0; it < 64; ++it) {
    int s = it * 256 + tid;
    int packed = pk;
    if (it < 63) pk = ws[WS_EIDS + ((s + 256) >> 1)];
    int eid = (s & 1) ? (packed >> 8) : (packed & 255);
    bool f = (eid == e);
    unsigned long long bal = __ballot(f);
    int lpre = __popcll(bal & ((1ull << lane) - 1ull));
    if (lane == 0) wsum[wid] = __popcll(bal);
    __syncthreads();
    int base = 0, tot = 0;
#pragma unroll
    for (int j = 0; j < 4; ++j) {
      int c = wsum[j];
      tot += c;
      if (j < wid) base += c;
    }
    int cur = cursor;
    __syncthreads();
    if (tid == 0) cursor = cur + tot;
    if (f) ws[WS_SLOTS + e * 16384 + cur + base + lpre] = s;
  }
  __syncthreads();
  if (tid == 0) ws[WS_COUNTS + e] = cursor;
}

// ---------------- scheduler: counts -> tile descriptors ---------------------
__global__ void sched_kernel(int* __restrict__ ws, int bm) {
  if (threadIdx.x == 0 && blockIdx.x == 0) {
    int nt = 0;
    for (int e = 0; e < NEXP; ++e) {
      int c = ws[WS_COUNTS + e];
      for (int m0 = 0; m0 < c; m0 += bm) {
        ws[WS_TDESC + nt * 2] = e;
        ws[WS_TDESC + nt * 2 + 1] = m0;
        ++nt;
      }
    }
    ws[WS_NTILES] = nt;
  }
}

// ---------------- one-time conversions (fast path) --------------------------
__global__ __launch_bounds__(256) void conv_x_kernel(
    const float* __restrict__ x, short* __restrict__ xbf) {
  size_t i8 = ((size_t)blockIdx.x * 256 + threadIdx.x) * 8;
  float4 f0 = *(const float4*)(x + i8);
  float4 f1 = *(const float4*)(x + i8 + 4);
  int4 o;
  o.x = (int)pack2_bf16(f0.x, f0.y);
  o.y = (int)pack2_bf16(f0.z, f0.w);
  o.z = (int)pack2_bf16(f1.x, f1.y);
  o.w = (int)pack2_bf16(f1.z, f1.w);
  *(int4*)(xbf + i8) = o;
}

// We[e][k][n] f32 -> We_t[e][n][k] bf16 (LDS tile transpose, +1 pad)
__global__ __launch_bounds__(256) void conv_wt_kernel(
    const float* __restrict__ We, short* __restrict__ wt) {
  __shared__ float tf[64][65];
  int b = blockIdx.x;
  int e = b >> 9;
  int rem = b & 511;
  int k0 = (rem >> 5) * 64;
  int n0 = (rem & 31) * 64;
  int tid = threadIdx.x;
  const float* src = We + (size_t)e * (EMBD * HIDD) + (size_t)k0 * HIDD + n0;
  int kr = tid >> 4;
  int n4 = (tid & 15) * 4;
#pragma unroll
  for (int ii = 0; ii < 4; ++ii) {
    float4 v = *(const float4*)(src + (size_t)(kr + 16 * ii) * HIDD + n4);
    tf[kr + 16 * ii][n4] = v.x;
    tf[kr + 16 * ii][n4 + 1] = v.y;
    tf[kr + 16 * ii][n4 + 2] = v.z;
    tf[kr + 16 * ii][n4 + 3] = v.w;
  }
  __syncthreads();
  int nr = tid >> 2;
  int kc = (tid & 3) * 16;
  short* dst = wt + (size_t)e * (HIDD * EMBD) + (size_t)(n0 + nr) * EMBD + k0 + kc;
  int4 o0, o1;
  o0.x = (int)pack2_bf16(tf[kc + 0][nr], tf[kc + 1][nr]);
  o0.y = (int)pack2_bf16(tf[kc + 2][nr], tf[kc + 3][nr]);
  o0.z = (int)pack2_bf16(tf[kc + 4][nr], tf[kc + 5][nr]);
  o0.w = (int)pack2_bf16(tf[kc + 6][nr], tf[kc + 7][nr]);
  o1.x = (int)pack2_bf16(tf[kc + 8][nr], tf[kc + 9][nr]);
  o1.y = (int)pack2_bf16(tf[kc + 10][nr], tf[kc + 11][nr]);
  o1.z = (int)pack2_bf16(tf[kc + 12][nr], tf[kc + 13][nr]);
  o1.w = (int)pack2_bf16(tf[kc + 14][nr], tf[kc + 15][nr]);
  *(int4*)dst = o0;
  *(int4*)(dst + 8) = o1;
}

// ---------------- fast grouped GEMM: bf16, 128x128x64, global_load_lds ------
// LDS A/B layout [128 rows][8 chunks of 16B]; chunk slot XOR-swizzled by
// (row&7) on BOTH source (pre-swizzled global addr) and ds_read (G4/rule 21).
#define MAXMT 136
__global__ __launch_bounds__(256) void expert_gemm_bf16(
    const short* __restrict__ xbf, const short* __restrict__ webf,
    const float* __restrict__ be, const int* __restrict__ ws,
    float* __restrict__ out) {
  __shared__ short lds_s[16384];  // A: [0,8192) shorts, B: [8192,16384)
  __shared__ int sslot[128];

  int nt = ws[WS_NTILES];
  int bid = blockIdx.x;
  int vid = (bid & 7) * 272 + (bid >> 3);  // bijective XCD swizzle (2176=8*272)
  int m_idx = vid % MAXMT;
  int n_idx = vid / MAXMT;
  if (m_idx >= nt) return;
  int e = ws[WS_TDESC + m_idx * 2];
  int m0 = ws[WS_TDESC + m_idx * 2 + 1];
  int cnt = ws[WS_COUNTS + e];
  int n0 = n_idx * 128;
  int tid = threadIdx.x;

  if (tid < 128) {
    int slot = -1;
    if (m0 + tid < cnt) slot = ws[WS_SLOTS + e * 16384 + m0 + tid];
    sslot[tid] = slot;
  }
  __syncthreads();

  // staging: thread -> (row = (tid>>3)+32i, chunk q = tid&7); source chunk
  // pre-swizzled: effq = q ^ (row&7); LDS dest linear = tid*16B + i*4096B
  int srow = tid >> 3;
  int effq = (tid & 7) ^ (srow & 7);
  const short* asrc[4];
  const short* bsrc[4];
  size_t webase = (size_t)e * (HIDD * EMBD);
#pragma unroll
  for (int i = 0; i < 4; ++i) {
    int r = srow + i * 32;
    int slot = sslot[r];
    int tok = (slot >= 0) ? (slot >> 1) : 0;
    asrc[i] = xbf + (size_t)tok * EMBD + effq * 8;
    bsrc[i] = webf + webase + (size_t)(n0 + r) * EMBD + effq * 8;
  }
  short* adst = lds_s + tid * 8;
  short* bdst = lds_s + 8192 + tid * 8;

  int lane = tid & 63, wv = tid >> 6;
  int wr = wv >> 1, wc = wv & 1;
  int lrow = lane & 15, lgrp = lane >> 4;

  f32x4 acc[4][4];
#pragma unroll
  for (int mi = 0; mi < 4; ++mi)
#pragma unroll
    for (int ni = 0; ni < 4; ++ni) acc[mi][ni] = (f32x4){0.f, 0.f, 0.f, 0.f};

#pragma unroll 1
  for (int k0 = 0; k0 < EMBD; k0 += 64) {
#pragma unroll
    for (int i = 0; i < 4; ++i) g2lds16(asrc[i] + k0, adst + i * 2048);
#pragma unroll
    for (int i = 0; i < 4; ++i) g2lds16(bsrc[i] + k0, bdst + i * 2048);
    __syncthreads();
#pragma unroll
    for (int kk = 0; kk < 2; ++kk) {
      short8 a[4], b[4];
#pragma unroll
      for (int mi = 0; mi < 4; ++mi) {
        int row = wr * 64 + mi * 16 + lrow;
        int c = (kk * 4 + lgrp) ^ (row & 7);
        a[mi] = *(const short8*)&lds_s[row * 64 + c * 8];
      }
#pragma unroll
      for (int ni = 0; ni < 4; ++ni) {
        int rn = wc * 64 + ni * 16 + lrow;
        int c = (kk * 4 + lgrp) ^ (rn & 7);
        b[ni] = *(const short8*)&lds_s[8192 + rn * 64 + c * 8];
      }
#pragma unroll
      for (int mi = 0; mi < 4; ++mi)
#pragma unroll
        for (int ni = 0; ni < 4; ++ni)
          acc[mi][ni] =
              __builtin_amdgcn_mfma_f32_16x16x32_bf16(a[mi], b[ni], acc[mi][ni], 0, 0, 0);
    }
    __syncthreads();
  }

  // epilogue: D layout col=lane&15, row=(lane>>4)*4+reg
#pragma unroll
  for (int ni = 0; ni < 4; ++ni) {
    int colg = n0 + wc * 64 + ni * 16 + lrow;
    float bev = be[(size_t)e * HIDD + colg];
#pragma unroll
    for (int mi = 0; mi < 4; ++mi) {
#pragma unroll
      for (int r = 0; r < 4; ++r) {
        int m = wr * 64 + mi * 16 + lgrp * 4 + r;
        int slot = sslot[m];
        if (slot >= 0)
          out[(size_t)T_TOKENS * 2 + (size_t)slot * HIDD + colg] =
              acc[mi][ni][r] + bev;
      }
    }
  }
}

// ---------------- fallback grouped GEMM (f32 in-kernel convert, 64x64) ------
#define BMF 64
#define LDT 72
__global__ __launch_bounds__(256) void expert_kernel_f32(
    const float* __restrict__ x, const float* __restrict__ We,
    const float* __restrict__ be, const int* __restrict__ ws,
    float* __restrict__ out) {
  __shared__ short As[BMF * LDT];
  __shared__ short Bs[64 * LDT];
  __shared__ int sslot[BMF];

  int nt = ws[WS_NTILES];
  if ((int)blockIdx.x >= nt) return;
  int e = ws[WS_TDESC + blockIdx.x * 2];
  int m0 = ws[WS_TDESC + blockIdx.x * 2 + 1];
  int cnt = ws[WS_COUNTS + e];
  int n0 = blockIdx.y * 64;

  int tid = threadIdx.x;
  if (tid < BMF) {
    int slot = -1;
    if (m0 + tid < cnt) slot = ws[WS_SLOTS + e * 16384 + m0 + tid];
    sslot[tid] = slot;
  }
  __syncthreads();

  int lane = tid & 63;
  int wid = tid >> 6;
  int wr = wid >> 1, wc = wid & 1;
  int lrow = lane & 15, lgrp = lane >> 4;

  f32x4 acc[2][2];
#pragma unroll
  for (int mi = 0; mi < 2; ++mi)
#pragma unroll
    for (int ni = 0; ni < 2; ++ni) acc[mi][ni] = (f32x4){0.f, 0.f, 0.f, 0.f};

  int arow = tid >> 2;
  int acq = (tid & 3) * 16;
  int aslot = sslot[arow];
  const float* abase = (aslot >= 0) ? (x + (size_t)(aslot >> 1) * EMBD + acq) : x;
  int bk = tid >> 2;
  int bnq = (tid & 3) * 16;
  const float* wbase = We + (size_t)e * EMBD * HIDD + (size_t)bk * HIDD + n0 + bnq;

#pragma unroll 1
  for (int ks = 0; ks < EMBD / 64; ++ks) {
    int k0 = ks * 64;
    {
      unsigned pk[8];
      if (aslot >= 0) {
        const float4* p = (const float4*)(abase + k0);
        float4 f0 = p[0], f1 = p[1], f2 = p[2], f3 = p[3];
        pk[0] = pack2_bf16(f0.x, f0.y); pk[1] = pack2_bf16(f0.z, f0.w);
        pk[2] = pack2_bf16(f1.x, f1.y); pk[3] = pack2_bf16(f1.z, f1.w);
        pk[4] = pack2_bf16(f2.x, f2.y); pk[5] = pack2_bf16(f2.z, f2.w);
        pk[6] = pack2_bf16(f3.x, f3.y); pk[7] = pack2_bf16(f3.z, f3.w);
      } else {
#pragma unroll
        for (int i = 0; i < 8; ++i) pk[i] = 0u;
      }
      int4* dst = (int4*)&As[arow * LDT + acq];
      dst[0] = make_int4((int)pk[0], (int)pk[1], (int)pk[2], (int)pk[3]);
      dst[1] = make_int4((int)pk[4], (int)pk[5], (int)pk[6], (int)pk[7]);
    }
    {
      const float4* p = (const float4*)(wbase + (size_t)k0 * HIDD);
      float4 f0 = p[0], f1 = p[1], f2 = p[2], f3 = p[3];
      float v[16] = {f0.x, f0.y, f0.z, f0.w, f1.x, f1.y, f1.z, f1.w,
                     f2.x, f2.y, f2.z, f2.w, f3.x, f3.y, f3.z, f3.w};
#pragma unroll
      for (int j = 0; j < 16; ++j) Bs[(bnq + j) * LDT + bk] = (short)bf16_1(v[j]);
    }
    __syncthreads();
#pragma unroll
    for (int kk = 0; kk < 2; ++kk) {
      short8 a0 = *(const short8*)&As[(wr * 32 + 0 + lrow) * LDT + kk * 32 + lgrp * 8];
      short8 a1 = *(const short8*)&As[(wr * 32 + 16 + lrow) * LDT + kk * 32 + lgrp * 8];
      short8 b0 = *(const short8*)&Bs[(wc * 32 + 0 + lrow) * LDT + kk * 32 + lgrp * 8];
      short8 b1 = *(const short8*)&Bs[(wc * 32 + 16 + lrow) * LDT + kk * 32 + lgrp * 8];
      acc[0][0] = __builtin_amdgcn_mfma_f32_16x16x32_bf16(a0, b0, acc[0][0], 0, 0, 0);
      acc[0][1] = __builtin_amdgcn_mfma_f32_16x16x32_bf16(a0, b1, acc[0][1], 0, 0, 0);
      acc[1][0] = __builtin_amdgcn_mfma_f32_16x16x32_bf16(a1, b0, acc[1][0], 0, 0, 0);
      acc[1][1] = __builtin_amdgcn_mfma_f32_16x16x32_bf16(a1, b1, acc[1][1], 0, 0, 0);
    }
    __syncthreads();
  }

#pragma unroll
  for (int ni = 0; ni < 2; ++ni) {
    int colg = n0 + wc * 32 + ni * 16 + lrow;
    float bev = be[(size_t)e * HIDD + colg];
#pragma unroll
    for (int mi = 0; mi < 2; ++mi) {
#pragma unroll
      for (int r = 0; r < 4; ++r) {
        int m = wr * 32 + mi * 16 + lgrp * 4 + r;
        int slot = sslot[m];
        if (slot >= 0)
          out[(size_t)T_TOKENS * 2 + (size_t)slot * HIDD + colg] =
              acc[mi][ni][r] + bev;
      }
    }
  }
}

extern "C" void kernel_launch(void* const* d_in, const int* in_sizes, int n_in,
                              void* d_out, int out_size, void* d_ws,
                              size_t ws_size, hipStream_t stream) {
  const float* x = (const float*)d_in[0];
  const float* Wg = (const float*)d_in[1];
  const float* bg = (const float*)d_in[2];
  const float* We = (const float*)d_in[3];
  const float* be = (const float*)d_in[4];
  float* out = (float*)d_out;
  int* ws = (int*)d_ws;

  bool fast = ws_size >= WS_NEED;

  gate_kernel<<<T_TOKENS / 4, 256, 0, stream>>>(x, Wg, bg, out, ws);
  lists_kernel<<<NEXP, 256, 0, stream>>>(ws);
  sched_kernel<<<1, 64, 0, stream>>>(ws, fast ? 128 : 64);

  if (fast) {
    short* xbf = (short*)((char*)d_ws + X_BF_OFF);
    short* webf = (short*)((char*)d_ws + WE_BF_OFF);
    conv_x_kernel<<<4096, 256, 0, stream>>>(x, xbf);
    conv_wt_kernel<<<4096, 256, 0, stream>>>(We, webf);
    expert_gemm_bf16<<<MAXMT * 16, 256, 0, stream>>>(xbf, webf, be, ws, out);
  } else {
    expert_kernel_f32<<<dim3(264, 32), 256, 0, stream>>>(x, We, be, ws, out);
  }
}

// Round 4
// 401.756 us; speedup vs baseline: 1.9885x; 1.0509x over previous
//
#include <hip/hip_runtime.h>
#include <hip/hip_bf16.h>

// B=4,S=2048 -> T=8192 tokens, EMB=1024, HID=2048, E=8, top-2 MoE.
// out = [top2_weights (T*2 f32)] ++ [top2_expert_outputs (T*2*HID f32)]
// Pipeline: gate(+x->bf16) -> scatter(wave-agg atomics) -> conv_wt -> GEMM.
// Expert-list order is correctness-irrelevant (each slot owns its out row).

#define T_TOKENS 8192
#define EMBD 1024
#define HIDD 2048
#define NEXP 8

// ws int layout
#define WS_COUNTS 0        // [8] padded: count e at ws[e*16] (64B apart)
#define WS_EIDS 1024       // [8192] packed i0|i1<<8
#define WS_SLOTS 17408     // [8][16384] slot = token*2 + k

// bf16 scratch region
#define X_BF_OFF ((size_t)1 << 20)
#define WE_BF_OFF (X_BF_OFF + (size_t)16777216)
#define WS_NEED (WE_BF_OFF + (size_t)33554432)

#define MAXMT 135          // sum ceil(cnt_e/128) <= 128 + 7
#define NTILE 16           // HIDD/128

typedef __attribute__((ext_vector_type(8))) short short8;
typedef __attribute__((ext_vector_type(4))) float f32x4;

__device__ __forceinline__ unsigned pack2_bf16(float a, float b) {
  unsigned ua = __float_as_uint(a);
  unsigned ub = __float_as_uint(b);
  ua = (ua + 0x7FFFu + ((ua >> 16) & 1u)) >> 16;  // RNE
  ub = (ub + 0x7FFFu + ((ub >> 16) & 1u)) >> 16;
  return ua | (ub << 16);
}

typedef __attribute__((address_space(3))) unsigned lds_u32;
typedef const __attribute__((address_space(1))) unsigned glb_u32;
__device__ __forceinline__ void g2lds16(const void* g, void* l) {
  __builtin_amdgcn_global_load_lds((glb_u32*)g, (lds_u32*)l, 16, 0, 0);
}

// ---------------- gating + x->bf16 conversion (fused) -----------------------
__global__ __launch_bounds__(256) void gate_kernel(
    const float* __restrict__ x, const float* __restrict__ Wg,
    const float* __restrict__ bg, float* __restrict__ out,
    int* __restrict__ ws, short* __restrict__ xbf) {
  int wid = threadIdx.x >> 6;
  int lane = threadIdx.x & 63;
  int t = blockIdx.x * 4 + wid;
  const float* xr = x + (size_t)t * EMBD;
  float acc[8];
#pragma unroll
  for (int e = 0; e < 8; ++e) acc[e] = 0.f;
#pragma unroll 4
  for (int i = lane; i < EMBD; i += 64) {
    float xv = xr[i];
    float4 w0 = *(const float4*)(Wg + (size_t)i * 8);
    float4 w1 = *(const float4*)(Wg + (size_t)i * 8 + 4);
    acc[0] += xv * w0.x; acc[1] += xv * w0.y;
    acc[2] += xv * w0.z; acc[3] += xv * w0.w;
    acc[4] += xv * w1.x; acc[5] += xv * w1.y;
    acc[6] += xv * w1.z; acc[7] += xv * w1.w;
  }
#pragma unroll
  for (int off = 32; off > 0; off >>= 1) {
#pragma unroll
    for (int e = 0; e < 8; ++e) acc[e] += __shfl_xor(acc[e], off);
  }
  if (lane == 0) {
    float lg[8];
#pragma unroll
    for (int e = 0; e < 8; ++e) lg[e] = acc[e] + bg[e];
    float mx = lg[0];
#pragma unroll
    for (int e = 1; e < 8; ++e) mx = fmaxf(mx, lg[e]);
    float w[8];
    float s = 0.f;
#pragma unroll
    for (int e = 0; e < 8; ++e) { w[e] = expf(lg[e] - mx); s += w[e]; }
    float inv = 1.f / s;
    int i0 = 0;
#pragma unroll
    for (int e = 1; e < 8; ++e) if (lg[e] > lg[i0]) i0 = e;
    int i1 = (i0 == 0) ? 1 : 0;
#pragma unroll
    for (int e = 0; e < 8; ++e) if (e != i0 && lg[e] > lg[i1]) i1 = e;
    out[(size_t)t * 2] = w[i0] * inv;
    out[(size_t)t * 2 + 1] = w[i1] * inv;
    ws[WS_EIDS + t] = i0 | (i1 << 8);
  }
  // ---- x -> bf16 (row is L2-hot); lane owns 16 consecutive floats
  const float* xc = xr + lane * 16;
  float4 f0 = *(const float4*)(xc);
  float4 f1 = *(const float4*)(xc + 4);
  float4 f2 = *(const float4*)(xc + 8);
  float4 f3 = *(const float4*)(xc + 12);
  int4 o0, o1;
  o0.x = (int)pack2_bf16(f0.x, f0.y); o0.y = (int)pack2_bf16(f0.z, f0.w);
  o0.z = (int)pack2_bf16(f1.x, f1.y); o0.w = (int)pack2_bf16(f1.z, f1.w);
  o1.x = (int)pack2_bf16(f2.x, f2.y); o1.y = (int)pack2_bf16(f2.z, f2.w);
  o1.z = (int)pack2_bf16(f3.x, f3.y); o1.w = (int)pack2_bf16(f3.z, f3.w);
  short* dst = xbf + (size_t)t * EMBD + lane * 16;
  *(int4*)dst = o0;
  *(int4*)(dst + 8) = o1;
}

// ---------------- scatter: wave-aggregated atomics --------------------------
__global__ __launch_bounds__(256) void scatter_kernel(int* __restrict__ ws) {
  int s = blockIdx.x * 256 + threadIdx.x;  // 64 blocks -> 16384 slots
  int lane = threadIdx.x & 63;
  int packed = ws[WS_EIDS + (s >> 1)];
  int eid = (s & 1) ? ((packed >> 8) & 255) : (packed & 255);
#pragma unroll
  for (int e = 0; e < 8; ++e) {
    bool f = (eid == e);
    unsigned long long bal = __ballot(f);
    if (bal) {
      int lpre = __popcll(bal & ((1ull << lane) - 1ull));
      int base = 0;
      if (lane == 0) base = atomicAdd(&ws[WS_COUNTS + e * 16], __popcll(bal));
      base = __shfl(base, 0);
      if (f) ws[WS_SLOTS + e * 16384 + base + lpre] = s;
    }
  }
}

// ---------------- We[e][k][n] f32 -> We_t[e][n][k] bf16 ---------------------
__global__ __launch_bounds__(256) void conv_wt_kernel(
    const float* __restrict__ We, short* __restrict__ wt) {
  __shared__ float tf[64][65];
  int b = blockIdx.x;
  int e = b >> 9;
  int rem = b & 511;
  int k0 = (rem >> 5) * 64;
  int n0 = (rem & 31) * 64;
  int tid = threadIdx.x;
  const float* src = We + (size_t)e * (EMBD * HIDD) + (size_t)k0 * HIDD + n0;
  int kr = tid >> 4;
  int n4 = (tid & 15) * 4;
#pragma unroll
  for (int ii = 0; ii < 4; ++ii) {
    float4 v = *(const float4*)(src + (size_t)(kr + 16 * ii) * HIDD + n4);
    tf[kr + 16 * ii][n4] = v.x;
    tf[kr + 16 * ii][n4 + 1] = v.y;
    tf[kr + 16 * ii][n4 + 2] = v.z;
    tf[kr + 16 * ii][n4 + 3] = v.w;
  }
  __syncthreads();
  int nr = tid >> 2;
  int kc = (tid & 3) * 16;
  short* dst = wt + (size_t)e * (HIDD * EMBD) + (size_t)(n0 + nr) * EMBD + k0 + kc;
  int4 o0, o1;
  o0.x = (int)pack2_bf16(tf[kc + 0][nr], tf[kc + 1][nr]);
  o0.y = (int)pack2_bf16(tf[kc + 2][nr], tf[kc + 3][nr]);
  o0.z = (int)pack2_bf16(tf[kc + 4][nr], tf[kc + 5][nr]);
  o0.w = (int)pack2_bf16(tf[kc + 6][nr], tf[kc + 7][nr]);
  o1.x = (int)pack2_bf16(tf[kc + 8][nr], tf[kc + 9][nr]);
  o1.y = (int)pack2_bf16(tf[kc + 10][nr], tf[kc + 11][nr]);
  o1.z = (int)pack2_bf16(tf[kc + 12][nr], tf[kc + 13][nr]);
  o1.w = (int)pack2_bf16(tf[kc + 14][nr], tf[kc + 15][nr]);
  *(int4*)dst = o0;
  *(int4*)(dst + 8) = o1;
}

// ---------------- grouped GEMM: bf16, 128x128x64, global_load_lds -----------
// Tile (expert,m0) derived from counts in-block; no tile table.
__global__ __launch_bounds__(256) void expert_gemm_bf16(
    const short* __restrict__ xbf, const short* __restrict__ webf,
    const float* __restrict__ be, const int* __restrict__ ws,
    float* __restrict__ out) {
  __shared__ short lds_s[16384];  // A: [0,8192) shorts, B: [8192,16384)
  __shared__ int sslot[128];

  int bid = blockIdx.x;
  int vid = (bid & 7) * (MAXMT * NTILE / 8) + (bid >> 3);  // bijective XCD swz
  int m_idx = vid % MAXMT;
  int n_idx = vid / MAXMT;

  // derive (e, m0, cnt) from counts
  int e = -1, m0 = 0, cnt = 0;
  {
    int acc = 0;
#pragma unroll
    for (int ee = 0; ee < 8; ++ee) {
      int c = ws[WS_COUNTS + ee * 16];
      int nte = (c + 127) >> 7;
      if (e < 0 && m_idx < acc + nte) { e = ee; m0 = (m_idx - acc) * 128; cnt = c; }
      acc += nte;
    }
  }
  if (e < 0) return;
  int n0 = n_idx * 128;
  int tid = threadIdx.x;

  if (tid < 128) {
    int slot = -1;
    if (m0 + tid < cnt) slot = ws[WS_SLOTS + e * 16384 + m0 + tid];
    sslot[tid] = slot;
  }
  __syncthreads();

  // staging: thread -> (row = (tid>>3)+32i, chunk q = tid&7); source chunk
  // pre-swizzled: effq = q ^ (row&7); LDS dest linear (rule 21 both-sides)
  int srow = tid >> 3;
  int effq = (tid & 7) ^ (srow & 7);
  const short* asrc[4];
  const short* bsrc[4];
  size_t webase = (size_t)e * (HIDD * EMBD);
#pragma unroll
  for (int i = 0; i < 4; ++i) {
    int r = srow + i * 32;
    int slot = sslot[r];
    int tok = (slot >= 0) ? (slot >> 1) : 0;
    asrc[i] = xbf + (size_t)tok * EMBD + effq * 8;
    bsrc[i] = webf + webase + (size_t)(n0 + r) * EMBD + effq * 8;
  }
  short* adst = lds_s + tid * 8;
  short* bdst = lds_s + 8192 + tid * 8;

  int lane = tid & 63, wv = tid >> 6;
  int wr = wv >> 1, wc = wv & 1;
  int lrow = lane & 15, lgrp = lane >> 4;

  f32x4 acc[4][4];
#pragma unroll
  for (int mi = 0; mi < 4; ++mi)
#pragma unroll
    for (int ni = 0; ni < 4; ++ni) acc[mi][ni] = (f32x4){0.f, 0.f, 0.f, 0.f};

#pragma unroll 1
  for (int k0 = 0; k0 < EMBD; k0 += 64) {
#pragma unroll
    for (int i = 0; i < 4; ++i) g2lds16(asrc[i] + k0, adst + i * 2048);
#pragma unroll
    for (int i = 0; i < 4; ++i) g2lds16(bsrc[i] + k0, bdst + i * 2048);
    __syncthreads();
#pragma unroll
    for (int kk = 0; kk < 2; ++kk) {
      short8 a[4], b[4];
#pragma unroll
      for (int mi = 0; mi < 4; ++mi) {
        int row = wr * 64 + mi * 16 + lrow;
        int c = (kk * 4 + lgrp) ^ (row & 7);
        a[mi] = *(const short8*)&lds_s[row * 64 + c * 8];
      }
#pragma unroll
      for (int ni = 0; ni < 4; ++ni) {
        int rn = wc * 64 + ni * 16 + lrow;
        int c = (kk * 4 + lgrp) ^ (rn & 7);
        b[ni] = *(const short8*)&lds_s[8192 + rn * 64 + c * 8];
      }
#pragma unroll
      for (int mi = 0; mi < 4; ++mi)
#pragma unroll
        for (int ni = 0; ni < 4; ++ni)
          acc[mi][ni] = __builtin_amdgcn_mfma_f32_16x16x32_bf16(
              a[mi], b[ni], acc[mi][ni], 0, 0, 0);
    }
    __syncthreads();
  }

  // epilogue: D layout col=lane&15, row=(lane>>4)*4+reg
#pragma unroll
  for (int ni = 0; ni < 4; ++ni) {
    int colg = n0 + wc * 64 + ni * 16 + lrow;
    float bev = be[(size_t)e * HIDD + colg];
#pragma unroll
    for (int mi = 0; mi < 4; ++mi) {
#pragma unroll
      for (int r = 0; r < 4; ++r) {
        int m = wr * 64 + mi * 16 + lgrp * 4 + r;
        int slot = sslot[m];
        if (slot >= 0)
          out[(size_t)T_TOKENS * 2 + (size_t)slot * HIDD + colg] =
              acc[mi][ni][r] + bev;
      }
    }
  }
}

extern "C" void kernel_launch(void* const* d_in, const int* in_sizes, int n_in,
                              void* d_out, int out_size, void* d_ws,
                              size_t ws_size, hipStream_t stream) {
  const float* x = (const float*)d_in[0];
  const float* Wg = (const float*)d_in[1];
  const float* bg = (const float*)d_in[2];
  const float* We = (const float*)d_in[3];
  const float* be = (const float*)d_in[4];
  float* out = (float*)d_out;
  int* ws = (int*)d_ws;
  short* xbf = (short*)((char*)d_ws + X_BF_OFF);
  short* webf = (short*)((char*)d_ws + WE_BF_OFF);

  hipMemsetAsync(d_ws, 0, 1024, stream);  // zero padded counters
  gate_kernel<<<T_TOKENS / 4, 256, 0, stream>>>(x, Wg, bg, out, ws, xbf);
  scatter_kernel<<<64, 256, 0, stream>>>(ws);
  conv_wt_kernel<<<4096, 256, 0, stream>>>(We, webf);
  expert_gemm_bf16<<<MAXMT * NTILE, 256, 0, stream>>>(xbf, webf, be, ws, out);
}

// Round 5
// 390.636 us; speedup vs baseline: 2.0451x; 1.0285x over previous
//
#include <hip/hip_runtime.h>
#include <hip/hip_bf16.h>

// B=4,S=2048 -> T=8192 tokens, EMB=1024, HID=2048, E=8, top-2 MoE.
// out = [top2_weights (T*2 f32)] ++ [top2_expert_outputs (T*2*HID f32)]
// Pipeline: gate(+x->bf16) -> scatter(wave-agg atomics) -> conv_wt ->
//           grouped GEMM (128x128x64, bf16 MFMA, 2-phase dbuf prefetch).

#define T_TOKENS 8192
#define EMBD 1024
#define HIDD 2048
#define NEXP 8

// ws int layout
#define WS_COUNTS 0        // [8] padded: count e at ws[e*16] (64B apart)
#define WS_EIDS 1024       // [8192] packed i0|i1<<8
#define WS_SLOTS 17408     // [8][16384] slot = token*2 + k

// bf16 scratch region
#define X_BF_OFF ((size_t)1 << 20)
#define WE_BF_OFF (X_BF_OFF + (size_t)16777216)

#define MAXMT 135          // sum ceil(cnt_e/128) <= 128 + 7
#define NTILE 16           // HIDD/128
// dynamic LDS: 2 bufs x 16384 shorts (A 8192 + B 8192) + 128 slot ints
#define LDS_BYTES (2 * 16384 * 2 + 128 * 4)

typedef __attribute__((ext_vector_type(8))) short short8;
typedef __attribute__((ext_vector_type(4))) float f32x4;

__device__ __forceinline__ unsigned pack2_bf16(float a, float b) {
  unsigned ua = __float_as_uint(a);
  unsigned ub = __float_as_uint(b);
  ua = (ua + 0x7FFFu + ((ua >> 16) & 1u)) >> 16;  // RNE
  ub = (ub + 0x7FFFu + ((ub >> 16) & 1u)) >> 16;
  return ua | (ub << 16);
}

typedef __attribute__((address_space(3))) unsigned lds_u32;
typedef const __attribute__((address_space(1))) unsigned glb_u32;
__device__ __forceinline__ void g2lds16(const void* g, void* l) {
  __builtin_amdgcn_global_load_lds((glb_u32*)g, (lds_u32*)l, 16, 0, 0);
}

// ---------------- gating + x->bf16 conversion (fused) -----------------------
__global__ __launch_bounds__(256) void gate_kernel(
    const float* __restrict__ x, const float* __restrict__ Wg,
    const float* __restrict__ bg, float* __restrict__ out,
    int* __restrict__ ws, short* __restrict__ xbf) {
  int wid = threadIdx.x >> 6;
  int lane = threadIdx.x & 63;
  int t = blockIdx.x * 4 + wid;
  const float* xr = x + (size_t)t * EMBD;
  float acc[8];
#pragma unroll
  for (int e = 0; e < 8; ++e) acc[e] = 0.f;
#pragma unroll 4
  for (int i = lane; i < EMBD; i += 64) {
    float xv = xr[i];
    float4 w0 = *(const float4*)(Wg + (size_t)i * 8);
    float4 w1 = *(const float4*)(Wg + (size_t)i * 8 + 4);
    acc[0] += xv * w0.x; acc[1] += xv * w0.y;
    acc[2] += xv * w0.z; acc[3] += xv * w0.w;
    acc[4] += xv * w1.x; acc[5] += xv * w1.y;
    acc[6] += xv * w1.z; acc[7] += xv * w1.w;
  }
#pragma unroll
  for (int off = 32; off > 0; off >>= 1) {
#pragma unroll
    for (int e = 0; e < 8; ++e) acc[e] += __shfl_xor(acc[e], off);
  }
  if (lane == 0) {
    float lg[8];
#pragma unroll
    for (int e = 0; e < 8; ++e) lg[e] = acc[e] + bg[e];
    float mx = lg[0];
#pragma unroll
    for (int e = 1; e < 8; ++e) mx = fmaxf(mx, lg[e]);
    float w[8];
    float s = 0.f;
#pragma unroll
    for (int e = 0; e < 8; ++e) { w[e] = expf(lg[e] - mx); s += w[e]; }
    float inv = 1.f / s;
    int i0 = 0;
#pragma unroll
    for (int e = 1; e < 8; ++e) if (lg[e] > lg[i0]) i0 = e;
    int i1 = (i0 == 0) ? 1 : 0;
#pragma unroll
    for (int e = 0; e < 8; ++e) if (e != i0 && lg[e] > lg[i1]) i1 = e;
    out[(size_t)t * 2] = w[i0] * inv;
    out[(size_t)t * 2 + 1] = w[i1] * inv;
    ws[WS_EIDS + t] = i0 | (i1 << 8);
  }
  // ---- x -> bf16 (row is L2-hot); lane owns 16 consecutive floats
  const float* xc = xr + lane * 16;
  float4 f0 = *(const float4*)(xc);
  float4 f1 = *(const float4*)(xc + 4);
  float4 f2 = *(const float4*)(xc + 8);
  float4 f3 = *(const float4*)(xc + 12);
  int4 o0, o1;
  o0.x = (int)pack2_bf16(f0.x, f0.y); o0.y = (int)pack2_bf16(f0.z, f0.w);
  o0.z = (int)pack2_bf16(f1.x, f1.y); o0.w = (int)pack2_bf16(f1.z, f1.w);
  o1.x = (int)pack2_bf16(f2.x, f2.y); o1.y = (int)pack2_bf16(f2.z, f2.w);
  o1.z = (int)pack2_bf16(f3.x, f3.y); o1.w = (int)pack2_bf16(f3.z, f3.w);
  short* dst = xbf + (size_t)t * EMBD + lane * 16;
  *(int4*)dst = o0;
  *(int4*)(dst + 8) = o1;
}

// ---------------- scatter: wave-aggregated atomics --------------------------
__global__ __launch_bounds__(256) void scatter_kernel(int* __restrict__ ws) {
  int s = blockIdx.x * 256 + threadIdx.x;  // 64 blocks -> 16384 slots
  int lane = threadIdx.x & 63;
  int packed = ws[WS_EIDS + (s >> 1)];
  int eid = (s & 1) ? ((packed >> 8) & 255) : (packed & 255);
#pragma unroll
  for (int e = 0; e < 8; ++e) {
    bool f = (eid == e);
    unsigned long long bal = __ballot(f);
    if (bal) {
      int lpre = __popcll(bal & ((1ull << lane) - 1ull));
      int base = 0;
      if (lane == 0) base = atomicAdd(&ws[WS_COUNTS + e * 16], __popcll(bal));
      base = __shfl(base, 0);
      if (f) ws[WS_SLOTS + e * 16384 + base + lpre] = s;
    }
  }
}

// ---------------- We[e][k][n] f32 -> We_t[e][n][k] bf16 ---------------------
__global__ __launch_bounds__(256) void conv_wt_kernel(
    const float* __restrict__ We, short* __restrict__ wt) {
  __shared__ float tf[64][65];
  int b = blockIdx.x;
  int e = b >> 9;
  int rem = b & 511;
  int k0 = (rem >> 5) * 64;
  int n0 = (rem & 31) * 64;
  int tid = threadIdx.x;
  const float* src = We + (size_t)e * (EMBD * HIDD) + (size_t)k0 * HIDD + n0;
  int kr = tid >> 4;
  int n4 = (tid & 15) * 4;
#pragma unroll
  for (int ii = 0; ii < 4; ++ii) {
    float4 v = *(const float4*)(src + (size_t)(kr + 16 * ii) * HIDD + n4);
    tf[kr + 16 * ii][n4] = v.x;
    tf[kr + 16 * ii][n4 + 1] = v.y;
    tf[kr + 16 * ii][n4 + 2] = v.z;
    tf[kr + 16 * ii][n4 + 3] = v.w;
  }
  __syncthreads();
  int nr = tid >> 2;
  int kc = (tid & 3) * 16;
  short* dst = wt + (size_t)e * (HIDD * EMBD) + (size_t)(n0 + nr) * EMBD + k0 + kc;
  int4 o0, o1;
  o0.x = (int)pack2_bf16(tf[kc + 0][nr], tf[kc + 1][nr]);
  o0.y = (int)pack2_bf16(tf[kc + 2][nr], tf[kc + 3][nr]);
  o0.z = (int)pack2_bf16(tf[kc + 4][nr], tf[kc + 5][nr]);
  o0.w = (int)pack2_bf16(tf[kc + 6][nr], tf[kc + 7][nr]);
  o1.x = (int)pack2_bf16(tf[kc + 8][nr], tf[kc + 9][nr]);
  o1.y = (int)pack2_bf16(tf[kc + 10][nr], tf[kc + 11][nr]);
  o1.z = (int)pack2_bf16(tf[kc + 12][nr], tf[kc + 13][nr]);
  o1.w = (int)pack2_bf16(tf[kc + 14][nr], tf[kc + 15][nr]);
  *(int4*)dst = o0;
  *(int4*)(dst + 8) = o1;
}

// ---------------- grouped GEMM: 128x128x64, 2-phase dbuf prefetch -----------
// T3 minimum recipe: STAGE(next) issued BEFORE compute(cur); ONE
// vmcnt(0)+barrier per K-tile (the __syncthreads drain covers both the
// prefetch completion and the LDS-read completion). LDS XOR-swizzle (rule 21
// both-sides: pre-swizzled global source, linear dest, swizzled ds_read).
__global__ __launch_bounds__(256) void expert_gemm_bf16(
    const short* __restrict__ xbf, const short* __restrict__ webf,
    const float* __restrict__ be, const int* __restrict__ ws,
    float* __restrict__ out) {
  extern __shared__ short smem[];  // [2][16384] shorts, then sslot[128] ints
  int* sslot = (int*)(smem + 32768);

  int bid = blockIdx.x;
  int vid = (bid & 7) * (MAXMT * NTILE / 8) + (bid >> 3);  // bijective XCD swz
  int m_idx = vid % MAXMT;
  int n_idx = vid / MAXMT;

  // derive (e, m0, cnt) from counts
  int e = -1, m0 = 0, cnt = 0;
  {
    int acc = 0;
#pragma unroll
    for (int ee = 0; ee < 8; ++ee) {
      int c = ws[WS_COUNTS + ee * 16];
      int nte = (c + 127) >> 7;
      if (e < 0 && m_idx < acc + nte) { e = ee; m0 = (m_idx - acc) * 128; cnt = c; }
      acc += nte;
    }
  }
  if (e < 0) return;
  int n0 = n_idx * 128;
  int tid = threadIdx.x;

  if (tid < 128) {
    int slot = -1;
    if (m0 + tid < cnt) slot = ws[WS_SLOTS + e * 16384 + m0 + tid];
    sslot[tid] = slot;
  }
  __syncthreads();

  // staging: thread -> (row = (tid>>3)+32i, chunk q = tid&7); source chunk
  // pre-swizzled: effq = q ^ (row&7); LDS dest linear
  int srow = tid >> 3;
  int effq = (tid & 7) ^ (srow & 7);
  const short* asrc[4];
  const short* bsrc[4];
  size_t webase = (size_t)e * (HIDD * EMBD);
#pragma unroll
  for (int i = 0; i < 4; ++i) {
    int r = srow + i * 32;
    int slot = sslot[r];
    int tok = (slot >= 0) ? (slot >> 1) : 0;
    asrc[i] = xbf + (size_t)tok * EMBD + effq * 8;
    bsrc[i] = webf + webase + (size_t)(n0 + r) * EMBD + effq * 8;
  }

  int lane = tid & 63, wv = tid >> 6;
  int wr = wv >> 1, wc = wv & 1;
  int lrow = lane & 15, lgrp = lane >> 4;

  f32x4 acc[4][4];
#pragma unroll
  for (int mi = 0; mi < 4; ++mi)
#pragma unroll
    for (int ni = 0; ni < 4; ++ni) acc[mi][ni] = (f32x4){0.f, 0.f, 0.f, 0.f};

#define STAGE(db, k0)                                                \
  {                                                                  \
    short* ad = smem + (db)*16384 + tid * 8;                         \
    short* bd = smem + (db)*16384 + 8192 + tid * 8;                  \
    _Pragma("unroll") for (int i = 0; i < 4; ++i)                    \
        g2lds16(asrc[i] + (k0), ad + i * 2048);                      \
    _Pragma("unroll") for (int i = 0; i < 4; ++i)                    \
        g2lds16(bsrc[i] + (k0), bd + i * 2048);                      \
  }

#define COMPUTE(db)                                                        \
  {                                                                        \
    const short* bufp = smem + (db)*16384;                                 \
    _Pragma("unroll") for (int kk = 0; kk < 2; ++kk) {                     \
      short8 a[4], b[4];                                                   \
      _Pragma("unroll") for (int mi = 0; mi < 4; ++mi) {                   \
        int row = wr * 64 + mi * 16 + lrow;                                \
        int c = (kk * 4 + lgrp) ^ (row & 7);                               \
        a[mi] = *(const short8*)&bufp[row * 64 + c * 8];                   \
      }                                                                    \
      _Pragma("unroll") for (int ni = 0; ni < 4; ++ni) {                   \
        int rn = wc * 64 + ni * 16 + lrow;                                 \
        int c = (kk * 4 + lgrp) ^ (rn & 7);                                \
        b[ni] = *(const short8*)&bufp[8192 + rn * 64 + c * 8];             \
      }                                                                    \
      _Pragma("unroll") for (int mi = 0; mi < 4; ++mi)                     \
          _Pragma("unroll") for (int ni = 0; ni < 4; ++ni) acc[mi][ni] =   \
              __builtin_amdgcn_mfma_f32_16x16x32_bf16(a[mi], b[ni],        \
                                                      acc[mi][ni], 0, 0, 0); \
    }                                                                      \
  }

  // prologue: fill buf0 with K-tile 0
  STAGE(0, 0);
  __syncthreads();
#pragma unroll 1
  for (int t = 0; t < 16; t += 2) {
    if (t + 1 < 16) STAGE(1, (t + 1) * 64);
    COMPUTE(0);
    __syncthreads();
    if (t + 2 < 16) STAGE(0, (t + 2) * 64);
    COMPUTE(1);
    __syncthreads();
  }
#undef STAGE
#undef COMPUTE

  // epilogue: D layout col=lane&15, row=(lane>>4)*4+reg
#pragma unroll
  for (int ni = 0; ni < 4; ++ni) {
    int colg = n0 + wc * 64 + ni * 16 + lrow;
    float bev = be[(size_t)e * HIDD + colg];
#pragma unroll
    for (int mi = 0; mi < 4; ++mi) {
#pragma unroll
      for (int r = 0; r < 4; ++r) {
        int m = wr * 64 + mi * 16 + lgrp * 4 + r;
        int slot = sslot[m];
        if (slot >= 0)
          out[(size_t)T_TOKENS * 2 + (size_t)slot * HIDD + colg] =
              acc[mi][ni][r] + bev;
      }
    }
  }
}

extern "C" void kernel_launch(void* const* d_in, const int* in_sizes, int n_in,
                              void* d_out, int out_size, void* d_ws,
                              size_t ws_size, hipStream_t stream) {
  const float* x = (const float*)d_in[0];
  const float* Wg = (const float*)d_in[1];
  const float* bg = (const float*)d_in[2];
  const float* We = (const float*)d_in[3];
  const float* be = (const float*)d_in[4];
  float* out = (float*)d_out;
  int* ws = (int*)d_ws;
  short* xbf = (short*)((char*)d_ws + X_BF_OFF);
  short* webf = (short*)((char*)d_ws + WE_BF_OFF);

  hipMemsetAsync(d_ws, 0, 1024, stream);  // zero padded counters
  gate_kernel<<<T_TOKENS / 4, 256, 0, stream>>>(x, Wg, bg, out, ws, xbf);
  scatter_kernel<<<64, 256, 0, stream>>>(ws);
  conv_wt_kernel<<<4096, 256, 0, stream>>>(We, webf);
  expert_gemm_bf16<<<MAXMT * NTILE, 256, LDS_BYTES, stream>>>(xbf, webf, be,
                                                              ws, out);
}